// Round 6
// baseline (529.863 us; speedup 1.0000x reference)
//
#include <hip/hip_runtime.h>
#include <math.h>

// BiMPM forward, fp32 throughout.
// Shapes: B=32, SA=SB=64, H=128, WD=300, L=20, V=50000, CLS=3
// Workspace layout (floats):
//   Gin   [4][32][64][512]  = 4194304   (reused for ctx then agg input projections)
//   ctxH  [4][32][64][128]  = 1048576   (chains: 0=A-f, 1=A-b, 2=B-f, 3=B-b)
//   att   [2][32][64][64]   = 262144
//   meanB [2][32][64][128]  = 524288
//   meanA [2][32][64][128]  = 524288
//   maxB  [2][32][64][128]  = 524288
//   maxA  [2][32][64][128]  = 524288
//   mv    [2][32][64][160]  = 655360    (mvA then mvB)
//   hfin  [32][512]         = 16384
// total ~31.6 MB

#define EPSV 1e-8f

__device__ __forceinline__ float sigm(float x) { return 1.f / (1.f + __expf(-x)); }
// Precise, overflow-safe tanh: t = expm1(-2|x|) in (-1,0]; tanh = sign(x) * -t/(t+2)
__device__ __forceinline__ float tanh_f(float x) {
    float t = expm1f(-2.f * fabsf(x));
    float r = -t / (t + 2.f);
    return copysignf(r, x);
}
__device__ __forceinline__ float divg(float n, float d) { return n / (d > EPSV ? d : EPSV); }
// Wave-uniform broadcast of lane `l`'s value (compile-time l after unroll).
__device__ __forceinline__ float rlane(float v, int l) {
    return __uint_as_float(__builtin_amdgcn_readlane(__float_as_uint(v), l));
}

// ---------------------------------------------------------------------------
// Input-projection GEMM: Gout = X @ W^T + (bih+bhh), scatter into
// Gin[chain][row][gate].  M=4096 rows (A rows 0..2047, B rows 2048+),
// N=1024 cols ([f 512 | b 512]).  GATHER: X row = word_emb[token[m]].
// R2 design: 64x64 tile, K_STEP=16, conflict-free staging, 8 KB LDS.
// (R4 bench: dropped out of top-5; leave untouched.)
// ---------------------------------------------------------------------------
template<bool GATHER>
__global__ __launch_bounds__(256)
void gemm_gin(const float* __restrict__ X,
              const int* __restrict__ tokA, const int* __restrict__ tokB,
              const float* __restrict__ emb,
              const float* __restrict__ Wf, const float* __restrict__ Wb,
              const float* __restrict__ bihF, const float* __restrict__ bhhF,
              const float* __restrict__ bihB, const float* __restrict__ bhhB,
              int K, float* __restrict__ Gout)
{
    const int tid = threadIdx.x;
    const int tx = tid & 15, ty = tid >> 4;
    const int m0 = blockIdx.x * 64;
    const int n0 = blockIdx.y * 64;
    const int dir = (n0 >= 512) ? 1 : 0;
    const float* Wd = dir ? Wb : Wf;
    const int nn0 = n0 & 511;

    __shared__ __align__(16) float As[16][64];
    __shared__ __align__(16) float Bs[16][64];

    const int sm = tid & 63;
    const int sq = tid >> 6;
    const int kq_off = sq << 2;

    const float* arow;
    if (GATHER) {
        const int mg = m0 + sm;
        const int tok = (mg < 2048) ? tokA[mg] : tokB[mg - 2048];
        arow = emb + (size_t)tok * 300;
    } else {
        arow = X + (size_t)(m0 + sm) * K;
    }
    const float* brow = Wd + (size_t)(nn0 + sm) * K;

    float acc[4][4];
#pragma unroll
    for (int r = 0; r < 4; ++r)
#pragma unroll
        for (int c = 0; c < 4; ++c) acc[r][c] = 0.f;

    float4 av = make_float4(0.f, 0.f, 0.f, 0.f);
    float4 bv = make_float4(0.f, 0.f, 0.f, 0.f);
    {
        const int kq = kq_off;
        if (kq + 4 <= K) {
            av = *(const float4*)(arow + kq);
            bv = *(const float4*)(brow + kq);
        }
    }

    for (int k0 = 0; k0 < K; k0 += 16) {
        __syncthreads();
        As[kq_off + 0][sm] = av.x;
        As[kq_off + 1][sm] = av.y;
        As[kq_off + 2][sm] = av.z;
        As[kq_off + 3][sm] = av.w;
        Bs[kq_off + 0][sm] = bv.x;
        Bs[kq_off + 1][sm] = bv.y;
        Bs[kq_off + 2][sm] = bv.z;
        Bs[kq_off + 3][sm] = bv.w;
        __syncthreads();

        av = make_float4(0.f, 0.f, 0.f, 0.f);
        bv = make_float4(0.f, 0.f, 0.f, 0.f);
        const int kq = k0 + 16 + kq_off;
        if (kq + 4 <= K) {
            av = *(const float4*)(arow + kq);
            bv = *(const float4*)(brow + kq);
        }

#pragma unroll
        for (int k = 0; k < 16; ++k) {
            float4 a = *(const float4*)(&As[k][ty << 2]);
            float4 b = *(const float4*)(&Bs[k][tx << 2]);
            acc[0][0] += a.x * b.x; acc[0][1] += a.x * b.y; acc[0][2] += a.x * b.z; acc[0][3] += a.x * b.w;
            acc[1][0] += a.y * b.x; acc[1][1] += a.y * b.y; acc[1][2] += a.y * b.z; acc[1][3] += a.y * b.w;
            acc[2][0] += a.z * b.x; acc[2][1] += a.z * b.y; acc[2][2] += a.z * b.z; acc[2][3] += a.z * b.w;
            acc[3][0] += a.w * b.x; acc[3][1] += a.w * b.y; acc[3][2] += a.w * b.z; acc[3][3] += a.w * b.w;
        }
    }

    const float* bih = dir ? bihB : bihF;
    const float* bhh = dir ? bhhB : bhhF;
    const int chain = ((m0 >= 2048) ? 2 : 0) + dir;
    const int nn = nn0 + (tx << 2);
    float b0 = bih[nn] + bhh[nn];
    float b1 = bih[nn + 1] + bhh[nn + 1];
    float b2 = bih[nn + 2] + bhh[nn + 2];
    float b3 = bih[nn + 3] + bhh[nn + 3];
#pragma unroll
    for (int r = 0; r < 4; ++r) {
        int m = m0 + (ty << 2) + r;
        int row = m & 2047;
        float4 o;
        o.x = acc[r][0] + b0; o.y = acc[r][1] + b1; o.z = acc[r][2] + b2; o.w = acc[r][3] + b3;
        *(float4*)(Gout + ((size_t)chain * 2048 + row) * 512 + nn) = o;
    }
}

// ---------------------------------------------------------------------------
// LSTM recurrence: 128 blocks = (chain 0..3) x (batch 0..31), 512 threads =
// one gate row each.
// R4 redesign (evidence: VGPR_Count=84 < 128 needed for w4 => weights were
// rematerialized/spilled; per-step ~2800cyc matches 256 LDS-broadcast-
// b128-issues/CU => LDS-issue-bound):
//   * h broadcast via v_readlane from lane-distributed VGPRs (2 ds_read_b32
//     per wave per step instead of 32 ds_read_b128 per THREAD per step)
//   * amdgpu_waves_per_eu(2,2): pin 2 waves/EU (grid is 128 blocks = 1
//     block/CU anyway) => 256-VGPR budget => w4[32] stays resident
//   * accumulation order identical to R2/R3 (bit-exact output preserved)
// ---------------------------------------------------------------------------
__global__ __launch_bounds__(512) __attribute__((amdgpu_waves_per_eu(2, 2)))
void lstm_kernel(const float* __restrict__ Gin,
                 const float* __restrict__ WhhF, const float* __restrict__ WhhB,
                 float* __restrict__ outH, float* __restrict__ hfin, int storeAll)
{
    const int tid = threadIdx.x;
    const int lane = tid & 63;
    const int chain = blockIdx.x >> 5;
    const int b = blockIdx.x & 31;
    const int rev = chain & 1;
    const float* Whh = rev ? WhhB : WhhF;

    __shared__ float hs[128];
    __shared__ float gact[512];

    float4 w4[32];
    const float4* wrow = (const float4*)(Whh + (size_t)tid * 128);
#pragma unroll
    for (int q = 0; q < 32; ++q) w4[q] = wrow[q];

    if (tid < 128) hs[tid] = 0.f;
    float c_reg = 0.f;
    __syncthreads();

    const size_t base = ((size_t)chain * 32 + b) * 64;
    float gin_cur = Gin[(base + (rev ? 63 : 0)) * 512 + tid];

    for (int t = 0; t < 64; ++t) {
        const int s_cur = rev ? 63 - t : t;
        float gin_next = 0.f;
        if (t + 1 < 64) {
            int s_next = rev ? 62 - t : t + 1;
            gin_next = Gin[(base + s_next) * 512 + tid];
        }
        // lane-distributed h: lane l holds h[l] (vh0) and h[64+l] (vh1)
        const float vh0 = hs[lane];
        const float vh1 = hs[64 + lane];
        float a0 = 0.f, a1 = 0.f, a2 = 0.f, a3 = 0.f;
#pragma unroll
        for (int q = 0; q < 16; ++q) {
            float4 w = w4[q];
            a0 += rlane(vh0, 4 * q + 0) * w.x;
            a1 += rlane(vh0, 4 * q + 1) * w.y;
            a2 += rlane(vh0, 4 * q + 2) * w.z;
            a3 += rlane(vh0, 4 * q + 3) * w.w;
        }
#pragma unroll
        for (int q = 16; q < 32; ++q) {
            float4 w = w4[q];
            a0 += rlane(vh1, 4 * q - 64) * w.x;
            a1 += rlane(vh1, 4 * q - 63) * w.y;
            a2 += rlane(vh1, 4 * q - 62) * w.z;
            a3 += rlane(vh1, 4 * q - 61) * w.w;
        }
        float g = gin_cur + ((a0 + a1) + (a2 + a3));
        gact[tid] = ((tid >> 7) == 2) ? tanh_f(g) : sigm(g);
        __syncthreads();
        if (tid < 128) {
            float iv = gact[tid], fv = gact[128 + tid], gv = gact[256 + tid], ov = gact[384 + tid];
            c_reg = fv * c_reg + iv * gv;
            float hv = ov * tanh_f(c_reg);
            hs[tid] = hv;
            if (storeAll) outH[(base + s_cur) * 128 + tid] = hv;
        }
        __syncthreads();
        gin_cur = gin_next;
    }
    if (!storeAll && tid < 128) hfin[(size_t)b * 512 + chain * 128 + tid] = hs[tid];
}

// ---------------------------------------------------------------------------
// Attention: att[dir][b][i][j] = cos(cA_dir[b,i], cB_dir[b,j]) with _div.
// ---------------------------------------------------------------------------
__global__ __launch_bounds__(256)
void attn_kernel(const float* __restrict__ ctxH, float* __restrict__ att)
{
    const int tid = threadIdx.x;
    const int b = blockIdx.x;
    const int dir = blockIdx.y;
    const float* cA = ctxH + (((size_t)dir * 32 + b) * 64) * 128;
    const float* cB = ctxH + (((size_t)(2 + dir) * 32 + b) * 64) * 128;
    __shared__ __align__(16) float sa[64 * 132];
    __shared__ __align__(16) float sb[64 * 132];
    __shared__ float na[64], nb[64];

    for (int e = tid; e < 8192; e += 256) {
        int i = e >> 7, k = e & 127;
        sa[i * 132 + k] = cA[e];
        sb[i * 132 + k] = cB[e];
    }
    __syncthreads();
    if (tid < 64) {
        float s = 0.f;
        for (int k = 0; k < 128; ++k) { float v = sa[tid * 132 + k]; s += v * v; }
        na[tid] = sqrtf(s);
    } else if (tid < 128) {
        int j = tid - 64; float s = 0.f;
        for (int k = 0; k < 128; ++k) { float v = sb[j * 132 + k]; s += v * v; }
        nb[j] = sqrtf(s);
    }
    __syncthreads();

    const int tx = tid & 15, ty = tid >> 4;
    float acc[4][4] = {};
    for (int k4 = 0; k4 < 32; ++k4) {
        float4 av[4], bv[4];
#pragma unroll
        for (int r = 0; r < 4; ++r) av[r] = *(const float4*)(sa + ((ty << 2) + r) * 132 + (k4 << 2));
#pragma unroll
        for (int c = 0; c < 4; ++c) bv[c] = *(const float4*)(sb + ((tx << 2) + c) * 132 + (k4 << 2));
#pragma unroll
        for (int r = 0; r < 4; ++r)
#pragma unroll
            for (int c = 0; c < 4; ++c)
                acc[r][c] += av[r].x * bv[c].x + av[r].y * bv[c].y + av[r].z * bv[c].z + av[r].w * bv[c].w;
    }
    float* attb = att + (((size_t)dir * 32 + b) * 64) * 64;
#pragma unroll
    for (int r = 0; r < 4; ++r) {
        int i = (ty << 2) + r;
#pragma unroll
        for (int c = 0; c < 4; ++c) {
            int j = (tx << 2) + c;
            attb[i * 64 + j] = divg(acc[r][c], na[i] * nb[j]);
        }
    }
}

// ---------------------------------------------------------------------------
// mean/max attentive aggregation.
// side 0: mean_B/max_B over j (targets from cB);  side 1: mean_A/max_A over i.
// ---------------------------------------------------------------------------
__global__ __launch_bounds__(256)
void meanmax_kernel(const float* __restrict__ ctxH, const float* __restrict__ att,
                    float* __restrict__ meanB, float* __restrict__ meanA,
                    float* __restrict__ maxB, float* __restrict__ maxA)
{
    const int tid = threadIdx.x;
    const int b = blockIdx.x, dir = blockIdx.y, side = blockIdx.z;
    __shared__ float sat[64 * 68];
    __shared__ __align__(16) float sc[64 * 132];
    __shared__ float ssum[64];

    const float* attb = att + (((size_t)dir * 32 + b) * 64) * 64;
    const int chain_src = side ? dir : (2 + dir);
    const float* cS = ctxH + (((size_t)chain_src * 32 + b) * 64) * 128;

    for (int e = tid; e < 4096; e += 256) sat[(e >> 6) * 68 + (e & 63)] = attb[e];
    for (int e = tid; e < 8192; e += 256) sc[(e >> 7) * 132 + (e & 127)] = cS[e];
    __syncthreads();
    if (tid < 64) {
        float s = 0.f;
        for (int q = 0; q < 64; ++q) s += side ? sat[q * 68 + tid] : sat[tid * 68 + q];
        ssum[tid] = s;
    }
    __syncthreads();

    const int r = tid >> 2;
    const int d0 = (tid & 3) * 32;
    float4 am[8], axv[8];
#pragma unroll
    for (int p = 0; p < 8; ++p) {
        am[p] = make_float4(0.f, 0.f, 0.f, 0.f);
        axv[p] = make_float4(-INFINITY, -INFINITY, -INFINITY, -INFINITY);
    }
    for (int q = 0; q < 64; ++q) {
        float a = side ? sat[q * 68 + r] : sat[r * 68 + q];
#pragma unroll
        for (int p = 0; p < 8; ++p) {
            float4 cv = *(const float4*)(sc + q * 132 + d0 + (p << 2));
            float px = a * cv.x, py = a * cv.y, pz = a * cv.z, pw = a * cv.w;
            am[p].x += px; am[p].y += py; am[p].z += pz; am[p].w += pw;
            axv[p].x = fmaxf(axv[p].x, px); axv[p].y = fmaxf(axv[p].y, py);
            axv[p].z = fmaxf(axv[p].z, pz); axv[p].w = fmaxf(axv[p].w, pw);
        }
    }
    float den = ssum[r] > EPSV ? ssum[r] : EPSV;
    float inv = 1.f / den;
    float* mout = (side ? meanA : meanB) + (((size_t)dir * 32 + b) * 64 + r) * 128 + d0;
    float* xout = (side ? maxA : maxB) + (((size_t)dir * 32 + b) * 64 + r) * 128 + d0;
#pragma unroll
    for (int p = 0; p < 8; ++p) {
        float4 o;
        o.x = am[p].x * inv; o.y = am[p].y * inv; o.z = am[p].z * inv; o.w = am[p].w * inv;
        *(float4*)(mout + (p << 2)) = o;
        *(float4*)(xout + (p << 2)) = axv[p];
    }
}

// ---------------------------------------------------------------------------
// Maxpool match: per (b, l, dir) weighted-cosine gram 64x64, then row/col max.
// Writes mv block 1 (f) / 5 (b).
// ---------------------------------------------------------------------------
__global__ __launch_bounds__(256)
void mm_kernel(const float* __restrict__ ctxH,
               const float* __restrict__ mpw3, const float* __restrict__ mpw4,
               float* __restrict__ mvA, float* __restrict__ mvB)
{
    const int tid = threadIdx.x;
    const int b = blockIdx.x, l = blockIdx.y, dir = blockIdx.z;
    const float* wsrc = (dir ? mpw4 : mpw3) + (size_t)l * 128;
    __shared__ float wl[128];
    __shared__ __align__(16) float su[64 * 132];
    __shared__ __align__(16) float sv[64 * 132];
    __shared__ float nu[64], nv[64];
    __shared__ float smm[64 * 68];

    const float* cA = ctxH + (((size_t)dir * 32 + b) * 64) * 128;
    const float* cB = ctxH + (((size_t)(2 + dir) * 32 + b) * 64) * 128;

    if (tid < 128) wl[tid] = wsrc[tid];
    __syncthreads();
    for (int e = tid; e < 8192; e += 256) {
        int i = e >> 7, k = e & 127;
        float w = wl[k];
        su[i * 132 + k] = cA[e] * w;
        sv[i * 132 + k] = cB[e] * w;
    }
    __syncthreads();
    if (tid < 64) {
        float s = 0.f;
        for (int k = 0; k < 128; ++k) { float v = su[tid * 132 + k]; s += v * v; }
        nu[tid] = sqrtf(s);
    } else if (tid < 128) {
        int j = tid - 64; float s = 0.f;
        for (int k = 0; k < 128; ++k) { float v = sv[j * 132 + k]; s += v * v; }
        nv[j] = sqrtf(s);
    }
    __syncthreads();

    const int tx = tid & 15, ty = tid >> 4;
    float acc[4][4] = {};
    for (int k4 = 0; k4 < 32; ++k4) {
        float4 av[4], bv[4];
#pragma unroll
        for (int r = 0; r < 4; ++r) av[r] = *(const float4*)(su + ((ty << 2) + r) * 132 + (k4 << 2));
#pragma unroll
        for (int c = 0; c < 4; ++c) bv[c] = *(const float4*)(sv + ((tx << 2) + c) * 132 + (k4 << 2));
#pragma unroll
        for (int r = 0; r < 4; ++r)
#pragma unroll
            for (int c = 0; c < 4; ++c)
                acc[r][c] += av[r].x * bv[c].x + av[r].y * bv[c].y + av[r].z * bv[c].z + av[r].w * bv[c].w;
    }
#pragma unroll
    for (int r = 0; r < 4; ++r) {
        int i = (ty << 2) + r;
#pragma unroll
        for (int c = 0; c < 4; ++c) {
            int j = (tx << 2) + c;
            smm[i * 68 + j] = divg(acc[r][c], nu[i] * nv[j]);
        }
    }
    __syncthreads();
    const int blkoff = (dir ? 5 : 1) * 20 + l;
    if (tid < 64) {
        float mx = -INFINITY;
        for (int j = 0; j < 64; ++j) mx = fmaxf(mx, smm[tid * 68 + j]);
        mvA[((size_t)b * 64 + tid) * 160 + blkoff] = mx;
    } else if (tid < 128) {
        int j = tid - 64;
        float mx = -INFINITY;
        for (int i = 0; i < 64; ++i) mx = fmaxf(mx, smm[i * 68 + j]);
        mvB[((size_t)b * 64 + j) * 160 + blkoff] = mx;
    }
}

// ---------------------------------------------------------------------------
// Full / attentive-mean / attentive-max matches (blocks 0,2,3 / 4,6,7).
// ---------------------------------------------------------------------------
__global__ __launch_bounds__(256)
void fm_kernel(const float* __restrict__ ctxH,
               const float* __restrict__ meanB, const float* __restrict__ meanA,
               const float* __restrict__ maxB, const float* __restrict__ maxA,
               const float* __restrict__ w1, const float* __restrict__ w2,
               const float* __restrict__ w5, const float* __restrict__ w6,
               const float* __restrict__ w7, const float* __restrict__ w8,
               float* __restrict__ mvA, float* __restrict__ mvB)
{
    const int tid = threadIdx.x;
    const int b = blockIdx.x, dir = blockIdx.y, side = blockIdx.z;
    __shared__ __align__(16) float sc[64 * 132];
    __shared__ __align__(16) float st[64 * 132];
    __shared__ __align__(16) float sw[20 * 132];

    const int chain_self = side ? (2 + dir) : dir;
    const float* cX = ctxH + (((size_t)chain_self * 32 + b) * 64) * 128;
    for (int e = tid; e < 8192; e += 256) sc[(e >> 7) * 132 + (e & 127)] = cX[e];

    for (int kind = 0; kind < 3; ++kind) {
        const float* w = (kind == 0) ? (dir ? w2 : w1)
                       : (kind == 1) ? (dir ? w6 : w5)
                                     : (dir ? w8 : w7);
        __syncthreads();   // covers initial sc staging + previous kind's readers
        if (kind == 0) {
            const int chain_o = side ? dir : (2 + dir);
            const float* trow = ctxH + (((size_t)chain_o * 32 + b) * 64 + (dir ? 0 : 63)) * 128;
            for (int e = tid; e < 128; e += 256) st[e] = trow[e];
        } else {
            const float* tsrc = (kind == 1) ? (side ? meanA : meanB) : (side ? maxA : maxB);
            tsrc += (((size_t)dir * 32 + b) * 64) * 128;
            for (int e = tid; e < 8192; e += 256) st[(e >> 7) * 132 + (e & 127)] = tsrc[e];
        }
        for (int e = tid; e < 2560; e += 256) sw[(e >> 7) * 132 + (e & 127)] = w[e];
        __syncthreads();

        const int blk = ((kind == 0) ? 0 : (kind == 1) ? 2 : 3) + (dir ? 4 : 0);
        float* mv = side ? mvB : mvA;
        for (int o = tid; o < 1280; o += 256) {
            int i = o / 20;
            int l = o - i * 20;
            const float* crow = sc + i * 132;
            const float* trow = st + ((kind == 0) ? 0 : i * 132);
            const float* wrow = sw + l * 132;
            float num = 0.f, na = 0.f, nb = 0.f;
#pragma unroll 8
            for (int k4 = 0; k4 < 32; ++k4) {
                float4 a = *(const float4*)(crow + (k4 << 2));
                float4 t = *(const float4*)(trow + (k4 << 2));
                float4 wv = *(const float4*)(wrow + (k4 << 2));
                float ax = a.x * wv.x, ay = a.y * wv.y, az = a.z * wv.z, aw = a.w * wv.w;
                float tx_ = t.x * wv.x, ty_ = t.y * wv.y, tz_ = t.z * wv.z, tw_ = t.w * wv.w;
                num += ax * tx_ + ay * ty_ + az * tz_ + aw * tw_;
                na  += ax * ax  + ay * ay  + az * az  + aw * aw;
                nb  += tx_ * tx_ + ty_ * ty_ + tz_ * tz_ + tw_ * tw_;
            }
            float den = sqrtf(na) * sqrtf(nb);
            mv[((size_t)b * 64 + i) * 160 + blk * 20 + l] = divg(num, den);
        }
    }
}

// ---------------------------------------------------------------------------
// Head: out = softmax(tanh(x @ fc1^T + b1) @ fc2^T + b2), one block per batch.
// ---------------------------------------------------------------------------
__global__ __launch_bounds__(256)
void head_kernel(const float* __restrict__ hfin,
                 const float* __restrict__ fc1W, const float* __restrict__ fc1b,
                 const float* __restrict__ fc2W, const float* __restrict__ fc2b,
                 float* __restrict__ out)
{
    const int b = blockIdx.x, tid = threadIdx.x;
    __shared__ __align__(16) float sx[512];
    __shared__ float sy[256], sl[3];
    for (int e = tid; e < 512; e += 256) sx[e] = hfin[(size_t)b * 512 + e];
    __syncthreads();
    {
        float acc = fc1b[tid];
        const float4* wr = (const float4*)(fc1W + (size_t)tid * 512);
#pragma unroll 8
        for (int k4 = 0; k4 < 128; ++k4) {
            float4 w = wr[k4];
            float4 x = *(const float4*)(sx + (k4 << 2));
            acc += w.x * x.x + w.y * x.y + w.z * x.z + w.w * x.w;
        }
        sy[tid] = tanh_f(acc);
    }
    __syncthreads();
    if (tid < 3) {
        float acc = fc2b[tid];
        for (int n = 0; n < 256; ++n) acc += sy[n] * fc2W[tid * 256 + n];
        sl[tid] = acc;
    }
    __syncthreads();
    if (tid < 3) {
        float m = fmaxf(sl[0], fmaxf(sl[1], sl[2]));
        float e0 = expf(sl[0] - m), e1 = expf(sl[1] - m), e2 = expf(sl[2] - m);
        float s = e0 + e1 + e2;
        float v = (tid == 0) ? e0 : ((tid == 1) ? e1 : e2);
        out[b * 3 + tid] = v / s;
    }
}

// ---------------------------------------------------------------------------
extern "C" void kernel_launch(void* const* d_in, const int* in_sizes, int n_in,
                              void* d_out, int out_size, void* d_ws, size_t ws_size,
                              hipStream_t stream)
{
    // Input index map.  setup_inputs() dict order has agg_Wih_f (81920) at
    // slot 7; reference-signature order would have ctx_Wih_b (153600) there.
    const bool dictOrder = (n_in > 7 && in_sizes[7] == 81920);
    int iCtxWih[2], iCtxWhh[2], iCtxBih[2], iCtxBhh[2];
    int iAggWih[2], iAggWhh[2], iAggBih[2], iAggBhh[2];
    int iW[8], iFc1W, iFc1b, iFc2W, iFc2b;
    if (dictOrder) {
        iCtxWih[0] = 3;  iCtxWhh[0] = 4;  iCtxBih[0] = 5;  iCtxBhh[0] = 6;
        iAggWih[0] = 7;  iAggWhh[0] = 8;  iAggBih[0] = 9;  iAggBhh[0] = 10;
        iCtxWih[1] = 11; iCtxWhh[1] = 12; iCtxBih[1] = 13; iCtxBhh[1] = 14;
        iAggWih[1] = 15; iAggWhh[1] = 16; iAggBih[1] = 17; iAggBhh[1] = 18;
        for (int k = 0; k < 8; ++k) iW[k] = 19 + k;
        iFc1W = 27; iFc1b = 28; iFc2W = 29; iFc2b = 30;
    } else {
        iCtxWih[0] = 3;  iCtxWhh[0] = 4;  iCtxBih[0] = 5;  iCtxBhh[0] = 6;
        iCtxWih[1] = 7;  iCtxWhh[1] = 8;  iCtxBih[1] = 9;  iCtxBhh[1] = 10;
        for (int k = 0; k < 8; ++k) iW[k] = 11 + k;
        iAggWih[0] = 19; iAggWhh[0] = 20; iAggBih[0] = 21; iAggBhh[0] = 22;
        iAggWih[1] = 23; iAggWhh[1] = 24; iAggBih[1] = 25; iAggBhh[1] = 26;
        iFc1W = 27; iFc1b = 28; iFc2W = 29; iFc2b = 30;
    }

    const int*   tokA = (const int*)d_in[0];
    const int*   tokB = (const int*)d_in[1];
    const float* emb  = (const float*)d_in[2];
    const float* ctxWihF = (const float*)d_in[iCtxWih[0]];
    const float* ctxWihB = (const float*)d_in[iCtxWih[1]];
    const float* ctxWhhF = (const float*)d_in[iCtxWhh[0]];
    const float* ctxWhhB = (const float*)d_in[iCtxWhh[1]];
    const float* ctxBihF = (const float*)d_in[iCtxBih[0]];
    const float* ctxBihB = (const float*)d_in[iCtxBih[1]];
    const float* ctxBhhF = (const float*)d_in[iCtxBhh[0]];
    const float* ctxBhhB = (const float*)d_in[iCtxBhh[1]];
    const float* aggWihF = (const float*)d_in[iAggWih[0]];
    const float* aggWihB = (const float*)d_in[iAggWih[1]];
    const float* aggWhhF = (const float*)d_in[iAggWhh[0]];
    const float* aggWhhB = (const float*)d_in[iAggWhh[1]];
    const float* aggBihF = (const float*)d_in[iAggBih[0]];
    const float* aggBihB = (const float*)d_in[iAggBih[1]];
    const float* aggBhhF = (const float*)d_in[iAggBhh[0]];
    const float* aggBhhB = (const float*)d_in[iAggBhh[1]];
    const float* mw[8];
    for (int k = 0; k < 8; ++k) mw[k] = (const float*)d_in[iW[k]];
    const float* fc1W = (const float*)d_in[iFc1W];
    const float* fc1b = (const float*)d_in[iFc1b];
    const float* fc2W = (const float*)d_in[iFc2W];
    const float* fc2b = (const float*)d_in[iFc2b];

    float* Wp    = (float*)d_ws;
    float* Gin   = Wp;
    float* ctxH  = Gin + 4194304;
    float* attw  = ctxH + 1048576;
    float* meanB = attw + 262144;
    float* meanA = meanB + 524288;
    float* maxB  = meanA + 524288;
    float* maxA  = maxB + 524288;
    float* mv    = maxA + 524288;
    float* hfin  = mv + 655360;
    float* mvA   = mv;
    float* mvB   = mv + (size_t)2048 * 160;

    dim3 gGemm(64, 16);

    // 1. ctx input projection (embedding gather)
    gemm_gin<true><<<gGemm, 256, 0, stream>>>(
        nullptr, tokA, tokB, emb, ctxWihF, ctxWihB,
        ctxBihF, ctxBhhF, ctxBihB, ctxBhhB, 300, Gin);

    // 2. ctx BiLSTM (store all timesteps)
    lstm_kernel<<<128, 512, 0, stream>>>(Gin, ctxWhhF, ctxWhhB, ctxH, hfin, 1);

    // 3. attention cosine matrices
    attn_kernel<<<dim3(32, 2), 256, 0, stream>>>(ctxH, attw);

    // 4. attentive mean / max targets
    meanmax_kernel<<<dim3(32, 2, 2), 256, 0, stream>>>(ctxH, attw, meanB, meanA, maxB, maxA);

    // 5. maxpool match (mv blocks 1,5)
    mm_kernel<<<dim3(32, 20, 2), 256, 0, stream>>>(ctxH, mw[2], mw[3], mvA, mvB);

    // 6. full / att-mean / att-max matches (mv blocks 0,2,3,4,6,7)
    fm_kernel<<<dim3(32, 2, 2), 256, 0, stream>>>(ctxH, meanB, meanA, maxB, maxA,
        mw[0], mw[1], mw[4], mw[5], mw[6], mw[7], mvA, mvB);

    // 7. agg input projection (reuse Gin)
    gemm_gin<false><<<gGemm, 256, 0, stream>>>(
        mv, nullptr, nullptr, nullptr, aggWihF, aggWihB,
        aggBihF, aggBhhF, aggBihB, aggBhhB, 160, Gin);

    // 8. agg BiLSTM (final states only)
    lstm_kernel<<<128, 512, 0, stream>>>(Gin, aggWhhF, aggWhhB, ctxH, hfin, 0);

    // 9. FC head + softmax
    head_kernel<<<32, 256, 0, stream>>>(hfin, fc1W, fc1b, fc2W, fc2b, (float*)d_out);

    (void)out_size; (void)ws_size;
}

// Round 10
// 480.883 us; speedup vs baseline: 1.1019x; 1.1019x over previous
//
#include <hip/hip_runtime.h>
#include <math.h>

// BiMPM forward, fp32 throughout.
// Shapes: B=32, SA=SB=64, H=128, WD=300, L=20, V=50000, CLS=3
// Workspace layout (floats):
//   Gin   [4][32][64][512]  = 4194304   (reused for ctx then agg input projections)
//   ctxH  [4][32][64][128]  = 1048576   (chains: 0=A-f, 1=A-b, 2=B-f, 3=B-b)
//   att   [2][32][64][64]   = 262144
//   meanB [2][32][64][128]  = 524288
//   meanA [2][32][64][128]  = 524288
//   maxB  [2][32][64][128]  = 524288
//   maxA  [2][32][64][128]  = 524288
//   mv    [2][32][64][160]  = 655360    (mvA then mvB)
//   hfin  [32][512]         = 16384
// total ~31.6 MB

#define EPSV 1e-8f

__device__ __forceinline__ float sigm(float x) { return 1.f / (1.f + __expf(-x)); }
// Intrinsic-only tanh (no ocml calls in the hot loop): (e-1)/(e+1), e=exp(2|x|).
// Clamp at 20 (tanh saturates ~9) so e never overflows -> no inf/inf.
__device__ __forceinline__ float tanh_f(float x) {
    float ax = fminf(fabsf(x), 20.f);
    float e = __expf(2.f * ax);
    float r = (e - 1.f) / (e + 1.f);
    return copysignf(r, x);
}
__device__ __forceinline__ float divg(float n, float d) { return n / (d > EPSV ? d : EPSV); }

// ---------------------------------------------------------------------------
// Input-projection GEMM: Gout = X @ W^T + (bih+bhh), scatter into
// Gin[chain][row][gate].  M=4096 rows (A rows 0..2047, B rows 2048+),
// N=1024 cols ([f 512 | b 512]).  GATHER: X row = word_emb[token[m]].
// R2 design: 64x64 tile, K_STEP=16, conflict-free staging, 8 KB LDS.
// (R4 bench: out of top-5; untouched.)
// ---------------------------------------------------------------------------
template<bool GATHER>
__global__ __launch_bounds__(256)
void gemm_gin(const float* __restrict__ X,
              const int* __restrict__ tokA, const int* __restrict__ tokB,
              const float* __restrict__ emb,
              const float* __restrict__ Wf, const float* __restrict__ Wb,
              const float* __restrict__ bihF, const float* __restrict__ bhhF,
              const float* __restrict__ bihB, const float* __restrict__ bhhB,
              int K, float* __restrict__ Gout)
{
    const int tid = threadIdx.x;
    const int tx = tid & 15, ty = tid >> 4;
    const int m0 = blockIdx.x * 64;
    const int n0 = blockIdx.y * 64;
    const int dir = (n0 >= 512) ? 1 : 0;
    const float* Wd = dir ? Wb : Wf;
    const int nn0 = n0 & 511;

    __shared__ __align__(16) float As[16][64];
    __shared__ __align__(16) float Bs[16][64];

    const int sm = tid & 63;
    const int sq = tid >> 6;
    const int kq_off = sq << 2;

    const float* arow;
    if (GATHER) {
        const int mg = m0 + sm;
        const int tok = (mg < 2048) ? tokA[mg] : tokB[mg - 2048];
        arow = emb + (size_t)tok * 300;
    } else {
        arow = X + (size_t)(m0 + sm) * K;
    }
    const float* brow = Wd + (size_t)(nn0 + sm) * K;

    float acc[4][4];
#pragma unroll
    for (int r = 0; r < 4; ++r)
#pragma unroll
        for (int c = 0; c < 4; ++c) acc[r][c] = 0.f;

    float4 av = make_float4(0.f, 0.f, 0.f, 0.f);
    float4 bv = make_float4(0.f, 0.f, 0.f, 0.f);
    {
        const int kq = kq_off;
        if (kq + 4 <= K) {
            av = *(const float4*)(arow + kq);
            bv = *(const float4*)(brow + kq);
        }
    }

    for (int k0 = 0; k0 < K; k0 += 16) {
        __syncthreads();
        As[kq_off + 0][sm] = av.x;
        As[kq_off + 1][sm] = av.y;
        As[kq_off + 2][sm] = av.z;
        As[kq_off + 3][sm] = av.w;
        Bs[kq_off + 0][sm] = bv.x;
        Bs[kq_off + 1][sm] = bv.y;
        Bs[kq_off + 2][sm] = bv.z;
        Bs[kq_off + 3][sm] = bv.w;
        __syncthreads();

        av = make_float4(0.f, 0.f, 0.f, 0.f);
        bv = make_float4(0.f, 0.f, 0.f, 0.f);
        const int kq = k0 + 16 + kq_off;
        if (kq + 4 <= K) {
            av = *(const float4*)(arow + kq);
            bv = *(const float4*)(brow + kq);
        }

#pragma unroll
        for (int k = 0; k < 16; ++k) {
            float4 a = *(const float4*)(&As[k][ty << 2]);
            float4 b = *(const float4*)(&Bs[k][tx << 2]);
            acc[0][0] += a.x * b.x; acc[0][1] += a.x * b.y; acc[0][2] += a.x * b.z; acc[0][3] += a.x * b.w;
            acc[1][0] += a.y * b.x; acc[1][1] += a.y * b.y; acc[1][2] += a.y * b.z; acc[1][3] += a.y * b.w;
            acc[2][0] += a.z * b.x; acc[2][1] += a.z * b.y; acc[2][2] += a.z * b.z; acc[2][3] += a.z * b.w;
            acc[3][0] += a.w * b.x; acc[3][1] += a.w * b.y; acc[3][2] += a.w * b.z; acc[3][3] += a.w * b.w;
        }
    }

    const float* bih = dir ? bihB : bihF;
    const float* bhh = dir ? bhhB : bhhF;
    const int chain = ((m0 >= 2048) ? 2 : 0) + dir;
    const int nn = nn0 + (tx << 2);
    float b0 = bih[nn] + bhh[nn];
    float b1 = bih[nn + 1] + bhh[nn + 1];
    float b2 = bih[nn + 2] + bhh[nn + 2];
    float b3 = bih[nn + 3] + bhh[nn + 3];
#pragma unroll
    for (int r = 0; r < 4; ++r) {
        int m = m0 + (ty << 2) + r;
        int row = m & 2047;
        float4 o;
        o.x = acc[r][0] + b0; o.y = acc[r][1] + b1; o.z = acc[r][2] + b2; o.w = acc[r][3] + b3;
        *(float4*)(Gout + ((size_t)chain * 2048 + row) * 512 + nn) = o;
    }
}

// ---------------------------------------------------------------------------
// LSTM recurrence, R6 K-split redesign.
// Evidence trail: R2 (LDS-broadcast) 74.9us and R4 (readlane) 94.6us both ran
// at VGPR_Count 84-88 -- the allocator refuses a 128-VGPR loop-carried weight
// array, so Whh was re-fetched from L2 every step: 128blk x 64steps x 256KB =
// 2.1 GB -> ~61us at 34.5 TB/s L2 = the observed time. Fix: design to the
// allocator's envelope. 1024 threads/block, thread = (gate row g, k-half):
// each thread holds only 16 float4 = 64 weight VGPRs. Partial sums combine in
// LDS; threads 0-127 fuse gates + update c,h. 2 barriers/step.
// ---------------------------------------------------------------------------
__global__ __launch_bounds__(1024, 4)
void lstm_kernel(const float* __restrict__ Gin,
                 const float* __restrict__ WhhF, const float* __restrict__ WhhB,
                 float* __restrict__ outH, float* __restrict__ hfin, int storeAll)
{
    const int tid = threadIdx.x;
    const int g = tid & 511;        // gate row
    const int kh = tid >> 9;        // 0: k in [0,64), 1: k in [64,128)
    const int chain = blockIdx.x >> 5;
    const int b = blockIdx.x & 31;
    const int rev = chain & 1;
    const float* Whh = rev ? WhhB : WhhF;

    __shared__ float4 hs4[32];      // h[128]
    __shared__ float pl[512];       // k-low partial (+ gin)
    __shared__ float ph[512];       // k-high partial
    float* hs = (float*)hs4;

    float4 w4[16];
    const float4* wrow = (const float4*)(Whh + (size_t)g * 128 + kh * 64);
#pragma unroll
    for (int q = 0; q < 16; ++q) w4[q] = wrow[q];

    if (tid < 128) hs[tid] = 0.f;
    float c_reg = 0.f;
    __syncthreads();

    const size_t base = ((size_t)chain * 32 + b) * 64;
    float gin_cur = 0.f;
    if (kh == 0) gin_cur = Gin[(base + (rev ? 63 : 0)) * 512 + g];

    const int qoff = kh << 4;       // hs4 quad offset: 0 or 16
    for (int t = 0; t < 64; ++t) {
        const int s_cur = rev ? 63 - t : t;
        float gin_next = 0.f;
        if (kh == 0 && t + 1 < 64) {
            int s_next = rev ? 62 - t : t + 1;
            gin_next = Gin[(base + s_next) * 512 + g];
        }
        float a0 = 0.f, a1 = 0.f, a2 = 0.f, a3 = 0.f;
#pragma unroll
        for (int q = 0; q < 16; ++q) {
            float4 h4 = hs4[qoff + q];     // wave-broadcast read
            float4 w = w4[q];
            a0 += h4.x * w.x; a1 += h4.y * w.y;
            a2 += h4.z * w.z; a3 += h4.w * w.w;
        }
        float a = (a0 + a1) + (a2 + a3);
        if (kh == 0) pl[g] = gin_cur + a; else ph[g] = a;
        __syncthreads();
        if (tid < 128) {
            float gi = pl[tid]       + ph[tid];
            float gf = pl[128 + tid] + ph[128 + tid];
            float gg = pl[256 + tid] + ph[256 + tid];
            float go = pl[384 + tid] + ph[384 + tid];
            float iv = sigm(gi), fv = sigm(gf), gv = tanh_f(gg), ov = sigm(go);
            c_reg = fv * c_reg + iv * gv;
            float hv = ov * tanh_f(c_reg);
            hs[tid] = hv;
            if (storeAll) outH[(base + s_cur) * 128 + tid] = hv;
        }
        __syncthreads();
        gin_cur = gin_next;
    }
    if (!storeAll && tid < 128) hfin[(size_t)b * 512 + chain * 128 + tid] = hs[tid];
}

// ---------------------------------------------------------------------------
// Attention: att[dir][b][i][j] = cos(cA_dir[b,i], cB_dir[b,j]) with _div.
// ---------------------------------------------------------------------------
__global__ __launch_bounds__(256)
void attn_kernel(const float* __restrict__ ctxH, float* __restrict__ att)
{
    const int tid = threadIdx.x;
    const int b = blockIdx.x;
    const int dir = blockIdx.y;
    const float* cA = ctxH + (((size_t)dir * 32 + b) * 64) * 128;
    const float* cB = ctxH + (((size_t)(2 + dir) * 32 + b) * 64) * 128;
    __shared__ __align__(16) float sa[64 * 132];
    __shared__ __align__(16) float sb[64 * 132];
    __shared__ float na[64], nb[64];

    for (int e = tid; e < 8192; e += 256) {
        int i = e >> 7, k = e & 127;
        sa[i * 132 + k] = cA[e];
        sb[i * 132 + k] = cB[e];
    }
    __syncthreads();
    if (tid < 64) {
        float s = 0.f;
        for (int k = 0; k < 128; ++k) { float v = sa[tid * 132 + k]; s += v * v; }
        na[tid] = sqrtf(s);
    } else if (tid < 128) {
        int j = tid - 64; float s = 0.f;
        for (int k = 0; k < 128; ++k) { float v = sb[j * 132 + k]; s += v * v; }
        nb[j] = sqrtf(s);
    }
    __syncthreads();

    const int tx = tid & 15, ty = tid >> 4;
    float acc[4][4] = {};
    for (int k4 = 0; k4 < 32; ++k4) {
        float4 av[4], bv[4];
#pragma unroll
        for (int r = 0; r < 4; ++r) av[r] = *(const float4*)(sa + ((ty << 2) + r) * 132 + (k4 << 2));
#pragma unroll
        for (int c = 0; c < 4; ++c) bv[c] = *(const float4*)(sb + ((tx << 2) + c) * 132 + (k4 << 2));
#pragma unroll
        for (int r = 0; r < 4; ++r)
#pragma unroll
            for (int c = 0; c < 4; ++c)
                acc[r][c] += av[r].x * bv[c].x + av[r].y * bv[c].y + av[r].z * bv[c].z + av[r].w * bv[c].w;
    }
    float* attb = att + (((size_t)dir * 32 + b) * 64) * 64;
#pragma unroll
    for (int r = 0; r < 4; ++r) {
        int i = (ty << 2) + r;
#pragma unroll
        for (int c = 0; c < 4; ++c) {
            int j = (tx << 2) + c;
            attb[i * 64 + j] = divg(acc[r][c], na[i] * nb[j]);
        }
    }
}

// ---------------------------------------------------------------------------
// mean/max attentive aggregation.
// side 0: mean_B/max_B over j (targets from cB);  side 1: mean_A/max_A over i.
// ---------------------------------------------------------------------------
__global__ __launch_bounds__(256)
void meanmax_kernel(const float* __restrict__ ctxH, const float* __restrict__ att,
                    float* __restrict__ meanB, float* __restrict__ meanA,
                    float* __restrict__ maxB, float* __restrict__ maxA)
{
    const int tid = threadIdx.x;
    const int b = blockIdx.x, dir = blockIdx.y, side = blockIdx.z;
    __shared__ float sat[64 * 68];
    __shared__ __align__(16) float sc[64 * 132];
    __shared__ float ssum[64];

    const float* attb = att + (((size_t)dir * 32 + b) * 64) * 64;
    const int chain_src = side ? dir : (2 + dir);
    const float* cS = ctxH + (((size_t)chain_src * 32 + b) * 64) * 128;

    for (int e = tid; e < 4096; e += 256) sat[(e >> 6) * 68 + (e & 63)] = attb[e];
    for (int e = tid; e < 8192; e += 256) sc[(e >> 7) * 132 + (e & 127)] = cS[e];
    __syncthreads();
    if (tid < 64) {
        float s = 0.f;
        for (int q = 0; q < 64; ++q) s += side ? sat[q * 68 + tid] : sat[tid * 68 + q];
        ssum[tid] = s;
    }
    __syncthreads();

    const int r = tid >> 2;
    const int d0 = (tid & 3) * 32;
    float4 am[8], axv[8];
#pragma unroll
    for (int p = 0; p < 8; ++p) {
        am[p] = make_float4(0.f, 0.f, 0.f, 0.f);
        axv[p] = make_float4(-INFINITY, -INFINITY, -INFINITY, -INFINITY);
    }
    for (int q = 0; q < 64; ++q) {
        float a = side ? sat[q * 68 + r] : sat[r * 68 + q];
#pragma unroll
        for (int p = 0; p < 8; ++p) {
            float4 cv = *(const float4*)(sc + q * 132 + d0 + (p << 2));
            float px = a * cv.x, py = a * cv.y, pz = a * cv.z, pw = a * cv.w;
            am[p].x += px; am[p].y += py; am[p].z += pz; am[p].w += pw;
            axv[p].x = fmaxf(axv[p].x, px); axv[p].y = fmaxf(axv[p].y, py);
            axv[p].z = fmaxf(axv[p].z, pz); axv[p].w = fmaxf(axv[p].w, pw);
        }
    }
    float den = ssum[r] > EPSV ? ssum[r] : EPSV;
    float inv = 1.f / den;
    float* mout = (side ? meanA : meanB) + (((size_t)dir * 32 + b) * 64 + r) * 128 + d0;
    float* xout = (side ? maxA : maxB) + (((size_t)dir * 32 + b) * 64 + r) * 128 + d0;
#pragma unroll
    for (int p = 0; p < 8; ++p) {
        float4 o;
        o.x = am[p].x * inv; o.y = am[p].y * inv; o.z = am[p].z * inv; o.w = am[p].w * inv;
        *(float4*)(mout + (p << 2)) = o;
        *(float4*)(xout + (p << 2)) = axv[p];
    }
}

// ---------------------------------------------------------------------------
// Maxpool match: per (b, l, dir) weighted-cosine gram 64x64, then row/col max.
// Writes mv block 1 (f) / 5 (b).
// ---------------------------------------------------------------------------
__global__ __launch_bounds__(256)
void mm_kernel(const float* __restrict__ ctxH,
               const float* __restrict__ mpw3, const float* __restrict__ mpw4,
               float* __restrict__ mvA, float* __restrict__ mvB)
{
    const int tid = threadIdx.x;
    const int b = blockIdx.x, l = blockIdx.y, dir = blockIdx.z;
    const float* wsrc = (dir ? mpw4 : mpw3) + (size_t)l * 128;
    __shared__ float wl[128];
    __shared__ __align__(16) float su[64 * 132];
    __shared__ __align__(16) float sv[64 * 132];
    __shared__ float nu[64], nv[64];
    __shared__ float smm[64 * 68];

    const float* cA = ctxH + (((size_t)dir * 32 + b) * 64) * 128;
    const float* cB = ctxH + (((size_t)(2 + dir) * 32 + b) * 64) * 128;

    if (tid < 128) wl[tid] = wsrc[tid];
    __syncthreads();
    for (int e = tid; e < 8192; e += 256) {
        int i = e >> 7, k = e & 127;
        float w = wl[k];
        su[i * 132 + k] = cA[e] * w;
        sv[i * 132 + k] = cB[e] * w;
    }
    __syncthreads();
    if (tid < 64) {
        float s = 0.f;
        for (int k = 0; k < 128; ++k) { float v = su[tid * 132 + k]; s += v * v; }
        nu[tid] = sqrtf(s);
    } else if (tid < 128) {
        int j = tid - 64; float s = 0.f;
        for (int k = 0; k < 128; ++k) { float v = sv[j * 132 + k]; s += v * v; }
        nv[j] = sqrtf(s);
    }
    __syncthreads();

    const int tx = tid & 15, ty = tid >> 4;
    float acc[4][4] = {};
    for (int k4 = 0; k4 < 32; ++k4) {
        float4 av[4], bv[4];
#pragma unroll
        for (int r = 0; r < 4; ++r) av[r] = *(const float4*)(su + ((ty << 2) + r) * 132 + (k4 << 2));
#pragma unroll
        for (int c = 0; c < 4; ++c) bv[c] = *(const float4*)(sv + ((tx << 2) + c) * 132 + (k4 << 2));
#pragma unroll
        for (int r = 0; r < 4; ++r)
#pragma unroll
            for (int c = 0; c < 4; ++c)
                acc[r][c] += av[r].x * bv[c].x + av[r].y * bv[c].y + av[r].z * bv[c].z + av[r].w * bv[c].w;
    }
#pragma unroll
    for (int r = 0; r < 4; ++r) {
        int i = (ty << 2) + r;
#pragma unroll
        for (int c = 0; c < 4; ++c) {
            int j = (tx << 2) + c;
            smm[i * 68 + j] = divg(acc[r][c], nu[i] * nv[j]);
        }
    }
    __syncthreads();
    const int blkoff = (dir ? 5 : 1) * 20 + l;
    if (tid < 64) {
        float mx = -INFINITY;
        for (int j = 0; j < 64; ++j) mx = fmaxf(mx, smm[tid * 68 + j]);
        mvA[((size_t)b * 64 + tid) * 160 + blkoff] = mx;
    } else if (tid < 128) {
        int j = tid - 64;
        float mx = -INFINITY;
        for (int i = 0; i < 64; ++i) mx = fmaxf(mx, smm[i * 68 + j]);
        mvB[((size_t)b * 64 + j) * 160 + blkoff] = mx;
    }
}

// ---------------------------------------------------------------------------
// Full / attentive-mean / attentive-max matches (blocks 0,2,3 / 4,6,7).
// ---------------------------------------------------------------------------
__global__ __launch_bounds__(256)
void fm_kernel(const float* __restrict__ ctxH,
               const float* __restrict__ meanB, const float* __restrict__ meanA,
               const float* __restrict__ maxB, const float* __restrict__ maxA,
               const float* __restrict__ w1, const float* __restrict__ w2,
               const float* __restrict__ w5, const float* __restrict__ w6,
               const float* __restrict__ w7, const float* __restrict__ w8,
               float* __restrict__ mvA, float* __restrict__ mvB)
{
    const int tid = threadIdx.x;
    const int b = blockIdx.x, dir = blockIdx.y, side = blockIdx.z;
    __shared__ __align__(16) float sc[64 * 132];
    __shared__ __align__(16) float st[64 * 132];
    __shared__ __align__(16) float sw[20 * 132];

    const int chain_self = side ? (2 + dir) : dir;
    const float* cX = ctxH + (((size_t)chain_self * 32 + b) * 64) * 128;
    for (int e = tid; e < 8192; e += 256) sc[(e >> 7) * 132 + (e & 127)] = cX[e];

    for (int kind = 0; kind < 3; ++kind) {
        const float* w = (kind == 0) ? (dir ? w2 : w1)
                       : (kind == 1) ? (dir ? w6 : w5)
                                     : (dir ? w8 : w7);
        __syncthreads();   // covers initial sc staging + previous kind's readers
        if (kind == 0) {
            const int chain_o = side ? dir : (2 + dir);
            const float* trow = ctxH + (((size_t)chain_o * 32 + b) * 64 + (dir ? 0 : 63)) * 128;
            for (int e = tid; e < 128; e += 256) st[e] = trow[e];
        } else {
            const float* tsrc = (kind == 1) ? (side ? meanA : meanB) : (side ? maxA : maxB);
            tsrc += (((size_t)dir * 32 + b) * 64) * 128;
            for (int e = tid; e < 8192; e += 256) st[(e >> 7) * 132 + (e & 127)] = tsrc[e];
        }
        for (int e = tid; e < 2560; e += 256) sw[(e >> 7) * 132 + (e & 127)] = w[e];
        __syncthreads();

        const int blk = ((kind == 0) ? 0 : (kind == 1) ? 2 : 3) + (dir ? 4 : 0);
        float* mv = side ? mvB : mvA;
        for (int o = tid; o < 1280; o += 256) {
            int i = o / 20;
            int l = o - i * 20;
            const float* crow = sc + i * 132;
            const float* trow = st + ((kind == 0) ? 0 : i * 132);
            const float* wrow = sw + l * 132;
            float num = 0.f, na = 0.f, nb = 0.f;
#pragma unroll 8
            for (int k4 = 0; k4 < 32; ++k4) {
                float4 a = *(const float4*)(crow + (k4 << 2));
                float4 t = *(const float4*)(trow + (k4 << 2));
                float4 wv = *(const float4*)(wrow + (k4 << 2));
                float ax = a.x * wv.x, ay = a.y * wv.y, az = a.z * wv.z, aw = a.w * wv.w;
                float tx_ = t.x * wv.x, ty_ = t.y * wv.y, tz_ = t.z * wv.z, tw_ = t.w * wv.w;
                num += ax * tx_ + ay * ty_ + az * tz_ + aw * tw_;
                na  += ax * ax  + ay * ay  + az * az  + aw * aw;
                nb  += tx_ * tx_ + ty_ * ty_ + tz_ * tz_ + tw_ * tw_;
            }
            float den = sqrtf(na) * sqrtf(nb);
            mv[((size_t)b * 64 + i) * 160 + blk * 20 + l] = divg(num, den);
        }
    }
}

// ---------------------------------------------------------------------------
// Head: out = softmax(tanh(x @ fc1^T + b1) @ fc2^T + b2), one block per batch.
// ---------------------------------------------------------------------------
__global__ __launch_bounds__(256)
void head_kernel(const float* __restrict__ hfin,
                 const float* __restrict__ fc1W, const float* __restrict__ fc1b,
                 const float* __restrict__ fc2W, const float* __restrict__ fc2b,
                 float* __restrict__ out)
{
    const int b = blockIdx.x, tid = threadIdx.x;
    __shared__ __align__(16) float sx[512];
    __shared__ float sy[256], sl[3];
    for (int e = tid; e < 512; e += 256) sx[e] = hfin[(size_t)b * 512 + e];
    __syncthreads();
    {
        float acc = fc1b[tid];
        const float4* wr = (const float4*)(fc1W + (size_t)tid * 512);
#pragma unroll 8
        for (int k4 = 0; k4 < 128; ++k4) {
            float4 w = wr[k4];
            float4 x = *(const float4*)(sx + (k4 << 2));
            acc += w.x * x.x + w.y * x.y + w.z * x.z + w.w * x.w;
        }
        sy[tid] = tanh_f(acc);
    }
    __syncthreads();
    if (tid < 3) {
        float acc = fc2b[tid];
        for (int n = 0; n < 256; ++n) acc += sy[n] * fc2W[tid * 256 + n];
        sl[tid] = acc;
    }
    __syncthreads();
    if (tid < 3) {
        float m = fmaxf(sl[0], fmaxf(sl[1], sl[2]));
        float e0 = expf(sl[0] - m), e1 = expf(sl[1] - m), e2 = expf(sl[2] - m);
        float s = e0 + e1 + e2;
        float v = (tid == 0) ? e0 : ((tid == 1) ? e1 : e2);
        out[b * 3 + tid] = v / s;
    }
}

// ---------------------------------------------------------------------------
extern "C" void kernel_launch(void* const* d_in, const int* in_sizes, int n_in,
                              void* d_out, int out_size, void* d_ws, size_t ws_size,
                              hipStream_t stream)
{
    // Input index map.  setup_inputs() dict order has agg_Wih_f (81920) at
    // slot 7; reference-signature order would have ctx_Wih_b (153600) there.
    const bool dictOrder = (n_in > 7 && in_sizes[7] == 81920);
    int iCtxWih[2], iCtxWhh[2], iCtxBih[2], iCtxBhh[2];
    int iAggWih[2], iAggWhh[2], iAggBih[2], iAggBhh[2];
    int iW[8], iFc1W, iFc1b, iFc2W, iFc2b;
    if (dictOrder) {
        iCtxWih[0] = 3;  iCtxWhh[0] = 4;  iCtxBih[0] = 5;  iCtxBhh[0] = 6;
        iAggWih[0] = 7;  iAggWhh[0] = 8;  iAggBih[0] = 9;  iAggBhh[0] = 10;
        iCtxWih[1] = 11; iCtxWhh[1] = 12; iCtxBih[1] = 13; iCtxBhh[1] = 14;
        iAggWih[1] = 15; iAggWhh[1] = 16; iAggBih[1] = 17; iAggBhh[1] = 18;
        for (int k = 0; k < 8; ++k) iW[k] = 19 + k;
        iFc1W = 27; iFc1b = 28; iFc2W = 29; iFc2b = 30;
    } else {
        iCtxWih[0] = 3;  iCtxWhh[0] = 4;  iCtxBih[0] = 5;  iCtxBhh[0] = 6;
        iCtxWih[1] = 7;  iCtxWhh[1] = 8;  iCtxBih[1] = 9;  iCtxBhh[1] = 10;
        for (int k = 0; k < 8; ++k) iW[k] = 11 + k;
        iAggWih[0] = 19; iAggWhh[0] = 20; iAggBih[0] = 21; iAggBhh[0] = 22;
        iAggWih[1] = 23; iAggWhh[1] = 24; iAggBih[1] = 25; iAggBhh[1] = 26;
        iFc1W = 27; iFc1b = 28; iFc2W = 29; iFc2b = 30;
    }

    const int*   tokA = (const int*)d_in[0];
    const int*   tokB = (const int*)d_in[1];
    const float* emb  = (const float*)d_in[2];
    const float* ctxWihF = (const float*)d_in[iCtxWih[0]];
    const float* ctxWihB = (const float*)d_in[iCtxWih[1]];
    const float* ctxWhhF = (const float*)d_in[iCtxWhh[0]];
    const float* ctxWhhB = (const float*)d_in[iCtxWhh[1]];
    const float* ctxBihF = (const float*)d_in[iCtxBih[0]];
    const float* ctxBihB = (const float*)d_in[iCtxBih[1]];
    const float* ctxBhhF = (const float*)d_in[iCtxBhh[0]];
    const float* ctxBhhB = (const float*)d_in[iCtxBhh[1]];
    const float* aggWihF = (const float*)d_in[iAggWih[0]];
    const float* aggWihB = (const float*)d_in[iAggWih[1]];
    const float* aggWhhF = (const float*)d_in[iAggWhh[0]];
    const float* aggWhhB = (const float*)d_in[iAggWhh[1]];
    const float* aggBihF = (const float*)d_in[iAggBih[0]];
    const float* aggBihB = (const float*)d_in[iAggBih[1]];
    const float* aggBhhF = (const float*)d_in[iAggBhh[0]];
    const float* aggBhhB = (const float*)d_in[iAggBhh[1]];
    const float* mw[8];
    for (int k = 0; k < 8; ++k) mw[k] = (const float*)d_in[iW[k]];
    const float* fc1W = (const float*)d_in[iFc1W];
    const float* fc1b = (const float*)d_in[iFc1b];
    const float* fc2W = (const float*)d_in[iFc2W];
    const float* fc2b = (const float*)d_in[iFc2b];

    float* Wp    = (float*)d_ws;
    float* Gin   = Wp;
    float* ctxH  = Gin + 4194304;
    float* attw  = ctxH + 1048576;
    float* meanB = attw + 262144;
    float* meanA = meanB + 524288;
    float* maxB  = meanA + 524288;
    float* maxA  = maxB + 524288;
    float* mv    = maxA + 524288;
    float* hfin  = mv + 655360;
    float* mvA   = mv;
    float* mvB   = mv + (size_t)2048 * 160;

    dim3 gGemm(64, 16);

    // 1. ctx input projection (embedding gather)
    gemm_gin<true><<<gGemm, 256, 0, stream>>>(
        nullptr, tokA, tokB, emb, ctxWihF, ctxWihB,
        ctxBihF, ctxBhhF, ctxBihB, ctxBhhB, 300, Gin);

    // 2. ctx BiLSTM (store all timesteps)
    lstm_kernel<<<128, 1024, 0, stream>>>(Gin, ctxWhhF, ctxWhhB, ctxH, hfin, 1);

    // 3. attention cosine matrices
    attn_kernel<<<dim3(32, 2), 256, 0, stream>>>(ctxH, attw);

    // 4. attentive mean / max targets
    meanmax_kernel<<<dim3(32, 2, 2), 256, 0, stream>>>(ctxH, attw, meanB, meanA, maxB, maxA);

    // 5. maxpool match (mv blocks 1,5)
    mm_kernel<<<dim3(32, 20, 2), 256, 0, stream>>>(ctxH, mw[2], mw[3], mvA, mvB);

    // 6. full / att-mean / att-max matches (mv blocks 0,2,3,4,6,7)
    fm_kernel<<<dim3(32, 2, 2), 256, 0, stream>>>(ctxH, meanB, meanA, maxB, maxA,
        mw[0], mw[1], mw[4], mw[5], mw[6], mw[7], mvA, mvB);

    // 7. agg input projection (reuse Gin)
    gemm_gin<false><<<gGemm, 256, 0, stream>>>(
        mv, nullptr, nullptr, nullptr, aggWihF, aggWihB,
        aggBihF, aggBhhF, aggBihB, aggBhhB, 160, Gin);

    // 8. agg BiLSTM (final states only)
    lstm_kernel<<<128, 1024, 0, stream>>>(Gin, aggWhhF, aggWhhB, ctxH, hfin, 0);

    // 9. FC head + softmax
    head_kernel<<<32, 256, 0, stream>>>(hfin, fc1W, fc1b, fc2W, fc2b, (float*)d_out);

    (void)out_size; (void)ws_size;
}